// Round 1
// baseline (709.130 us; speedup 1.0000x reference)
//
#include <hip/hip_runtime.h>
#include <hip/hip_bf16.h>

// PPNet head for MI355X.
// Pipeline: prep (weight transpose + proto norms) -> conv+sigmoid (channel-last f)
//           -> distances+log acts -> spatial max -> logits.
// All fp32 (no fp32 MFMA on CDNA4; both conv and einsum are VALU work).

#define H_OUT 128
#define W_OUT 128
#define C_F   64
#define N_P   190
#define N_CLS 19
#define N_B   16
#define EPS_F 1e-4f

// ---------------- prep: transpose conv weights + prototype squared norms ----
// w_t[k][co] = feat_w[co][k],  k = ci*49 + kh*7 + kw   (147 x 64)
// fsum[p] = sum_c proto[p][c]^2
__global__ void prep_kernel(const float* __restrict__ feat_w,
                            const float* __restrict__ proto,
                            float* __restrict__ w_t,
                            float* __restrict__ fsum) {
    int t = blockIdx.x * 256 + threadIdx.x;
    if (t < 147 * 64) {
        int co = t & 63;
        int k  = t >> 6;
        w_t[t] = feat_w[co * 147 + k];
    }
    if (t < N_P) {
        float s = 0.f;
        for (int c = 0; c < C_F; ++c) {
            float v = proto[t * C_F + c];
            s = fmaf(v, v, s);
        }
        fsum[t] = s;
    }
}

// ---------------- conv 7x7 s4 p3 + bias + sigmoid, channel-last output -----
// One block per (b, oh) row: 128 positions x 64 channels.
// Thread: ow = tid&127, channel half = tid>>7 (wave-uniform -> weights via s_load).
// LDS: 21 input rows (3 ci x 7 kh), swizzled phys = iw' + (iw'>>5) so the
// stride-4 patch reads hit 32 distinct banks (2-way aliasing = free).
#define ROWP 532
__global__ __launch_bounds__(256) void conv_kernel(const float* __restrict__ x,
                                                   const float* __restrict__ w_t,
                                                   const float* __restrict__ bias,
                                                   float* __restrict__ f_t) {
    __shared__ float xs[21 * ROWP];
    const int bid = blockIdx.x;
    const int b = bid >> 7;
    const int oh = bid & 127;
    const int tid = threadIdx.x;

    // zero LDS (covers left pad + swizzle gaps)
    for (int i = tid; i < 21 * ROWP; i += 256) xs[i] = 0.f;
    __syncthreads();

    // stage 21 rows x 512 floats, coalesced global reads
    for (int i = tid; i < 21 * 512; i += 256) {
        int row = i >> 9;          // ci*7 + kh
        int iw  = i & 511;
        int ci = row / 7;
        int kh = row - ci * 7;
        int ih = oh * 4 - 3 + kh;  // [-3, 511]
        float v = 0.f;
        if (ih >= 0) v = x[((b * 3 + ci) * 512 + ih) * 512 + iw];
        int iwp = iw + 3;
        xs[row * ROWP + iwp + (iwp >> 5)] = v;
    }
    __syncthreads();

    const int ow = tid & 127;
    const int half = tid >> 7;                             // 0 or 1, uniform per wave
    const int half_u = __builtin_amdgcn_readfirstlane(half);

    float acc[32];
#pragma unroll
    for (int j = 0; j < 32; ++j) acc[j] = 0.f;

    for (int row = 0; row < 21; ++row) {
#pragma unroll
        for (int kw = 0; kw < 7; ++kw) {
            int iwp = ow * 4 + kw;
            float xv = xs[row * ROWP + iwp + (iwp >> 5)];
            const float* wp = w_t + (row * 7 + kw) * 64 + half_u * 32;  // uniform -> s_load
#pragma unroll
            for (int j = 0; j < 32; ++j) acc[j] = fmaf(xv, wp[j], acc[j]);
        }
    }

    // bias + sigmoid, store channel-last: f_t[(b*16384 + oh*128 + ow)*64 + c]
    const int c0 = half * 32;
    float* out = f_t + ((long)(b * 16384 + oh * 128 + ow)) * 64 + c0;
#pragma unroll
    for (int j = 0; j < 32; j += 4) {
        float4 v;
        float z0 = acc[j + 0] + bias[c0 + j + 0];
        float z1 = acc[j + 1] + bias[c0 + j + 1];
        float z2 = acc[j + 2] + bias[c0 + j + 2];
        float z3 = acc[j + 3] + bias[c0 + j + 3];
        v.x = 1.f / (1.f + __expf(-z0));
        v.y = 1.f / (1.f + __expf(-z1));
        v.z = 1.f / (1.f + __expf(-z2));
        v.w = 1.f / (1.f + __expf(-z3));
        *(float4*)(out + j) = v;
    }
}

// ---------------- distances + log activations ------------------------------
// One thread per pixel; f-vec (64 fp32) in VGPRs, reused across all 190
// prototypes. Prototype values are block-uniform -> scalar loads. 4
// independent FMA chains for ILP. Stores coalesced (lane = consecutive pixel).
__global__ __launch_bounds__(256) void pp_kernel(const float* __restrict__ f_t,
                                                 const float* __restrict__ proto,
                                                 const float* __restrict__ fsum,
                                                 float* __restrict__ acts) {
    const int b = blockIdx.x >> 6;
    const int pos = (blockIdx.x & 63) * 256 + threadIdx.x;  // 0..16383

    const float4* fv = (const float4*)(f_t + ((long)(b * 16384 + pos)) * C_F);
    float f[C_F];
#pragma unroll
    for (int c4 = 0; c4 < 16; ++c4) {
        float4 v = fv[c4];
        f[4 * c4 + 0] = v.x; f[4 * c4 + 1] = v.y;
        f[4 * c4 + 2] = v.z; f[4 * c4 + 3] = v.w;
    }

    float ps = 0.f;
#pragma unroll
    for (int c = 0; c < C_F; ++c) ps = fmaf(f[c], f[c], ps);

    float* out = acts + (long)b * N_P * 16384 + pos;
    for (int p = 0; p < N_P; ++p) {
        const float* wp = proto + p * C_F;   // uniform -> s_load
        float a0 = 0.f, a1 = 0.f, a2 = 0.f, a3 = 0.f;
#pragma unroll
        for (int c = 0; c < C_F; c += 4) {
            a0 = fmaf(f[c + 0], wp[c + 0], a0);
            a1 = fmaf(f[c + 1], wp[c + 1], a1);
            a2 = fmaf(f[c + 2], wp[c + 2], a2);
            a3 = fmaf(f[c + 3], wp[c + 3], a3);
        }
        float cc = (a0 + a1) + (a2 + a3);
        float d = ps - 2.f * cc + fsum[p];
        float act = __logf(__fdividef(d + 1.f, d + EPS_F));
        out[(long)p * 16384] = act;
    }
}

// ---------------- spatial max over 128x128 per (b,p) -----------------------
__global__ __launch_bounds__(256) void pool_kernel(const float* __restrict__ acts,
                                                   float* __restrict__ pooled) {
    const int idx = blockIdx.x;  // b*190 + p
    const float4* base = (const float4*)(acts + (long)idx * 16384);
    float m = -3.4e38f;
    for (int i = threadIdx.x; i < 4096; i += 256) {
        float4 v = base[i];
        m = fmaxf(m, fmaxf(fmaxf(v.x, v.y), fmaxf(v.z, v.w)));
    }
#pragma unroll
    for (int off = 32; off; off >>= 1) m = fmaxf(m, __shfl_down(m, off, 64));
    __shared__ float sm[4];
    int lane = threadIdx.x & 63, wv = threadIdx.x >> 6;
    if (lane == 0) sm[wv] = m;
    __syncthreads();
    if (threadIdx.x == 0)
        pooled[idx] = fmaxf(fmaxf(sm[0], sm[1]), fmaxf(sm[2], sm[3]));
}

// ---------------- logits = pooled @ last_w^T -------------------------------
__global__ void logits_kernel(const float* __restrict__ pooled,
                              const float* __restrict__ last_w,
                              float* __restrict__ logits) {
    int t = blockIdx.x * blockDim.x + threadIdx.x;
    if (t >= N_B * N_CLS) return;
    int b = t / N_CLS, cls = t - b * N_CLS;
    float s = 0.f;
    for (int p = 0; p < N_P; ++p)
        s = fmaf(pooled[b * N_P + p], last_w[cls * N_P + p], s);
    logits[t] = s;
}

extern "C" void kernel_launch(void* const* d_in, const int* in_sizes, int n_in,
                              void* d_out, int out_size, void* d_ws, size_t ws_size,
                              hipStream_t stream) {
    const float* x      = (const float*)d_in[0];  // (16,3,512,512)
    const float* feat_w = (const float*)d_in[1];  // (64,3,7,7)
    const float* feat_b = (const float*)d_in[2];  // (64,)
    const float* proto  = (const float*)d_in[3];  // (190,64,1,1)
    const float* last_w = (const float*)d_in[4];  // (19,190)

    float* out_logits = (float*)d_out;            // 304 floats
    float* out_acts   = (float*)d_out + N_B * N_CLS;  // 16*190*128*128 floats

    // ws layout
    char* ws = (char*)d_ws;
    float* f_t   = (float*)(ws);                                  // 67,108,864 B
    float* w_t   = (float*)(ws + 67108864);                       // 37,632 B
    float* fsum  = (float*)(ws + 67108864 + 37632);               // 760 B
    float* pooled = (float*)(ws + 67108864 + 37632 + 1024);       // 12,160 B

    prep_kernel<<<37, 256, 0, stream>>>(feat_w, proto, w_t, fsum);
    conv_kernel<<<N_B * H_OUT, 256, 0, stream>>>(x, w_t, feat_b, f_t);
    pp_kernel<<<N_B * 64, 256, 0, stream>>>(f_t, proto, fsum, out_acts);
    pool_kernel<<<N_B * N_P, 256, 0, stream>>>(out_acts, pooled);
    logits_kernel<<<2, 256, 0, stream>>>(pooled, last_w, out_logits);
}

// Round 2
// 443.784 us; speedup vs baseline: 1.5979x; 1.5979x over previous
//
#include <hip/hip_runtime.h>
#include <hip/hip_bf16.h>

// PPNet head for MI355X, round 2.
// prep -> conv(fp32 VALU, writes bf16 f channel-last + fp32 ps)
//      -> pp (bf16 MFMA cc + log acts + fused in-wave max-pool partials)
//      -> final (256-way max reduce + logits).
// pp round-1 was s_load-latency bound (VALUBusy 40%); MFMA + direct frag
// loads (channel-last => every lane's 16B load is contiguous) removes it.

#define N_P   190
#define N_CLS 19
#define N_B   16
#define EPS_F 1e-4f
#define PIX   16384

typedef unsigned short ushort_t;
typedef unsigned int   uint_t;
typedef __attribute__((ext_vector_type(8))) short bf16x8;
typedef __attribute__((ext_vector_type(4))) float f32x4;

__device__ __forceinline__ ushort_t bf16_rne(float v) {
    uint_t u = __float_as_uint(v);
    u += 0x7fffu + ((u >> 16) & 1u);
    return (ushort_t)(u >> 16);
}

// ---------------- prep: w_t transpose, proto bf16 (pad to 192), fsum -------
__global__ void prep_kernel(const float* __restrict__ feat_w,
                            const float* __restrict__ proto,
                            float* __restrict__ w_t,
                            ushort_t* __restrict__ proto_bf,
                            float* __restrict__ fsum) {
    int t = blockIdx.x * 256 + threadIdx.x;   // grid 48*256 = 12288
    if (t < 147 * 64) {
        int co = t & 63, k = t >> 6;
        w_t[t] = feat_w[co * 147 + k];
    }
    if (t < 192 * 64) {
        int p = t >> 6, c = t & 63;
        float v = (p < N_P) ? proto[p * 64 + c] : 0.f;
        proto_bf[t] = bf16_rne(v);
    }
    if (t < 192) {
        float s = 0.f;
        if (t < N_P)
            for (int c = 0; c < 64; ++c) {
                float v = proto[t * 64 + c];
                s = fmaf(v, v, s);
            }
        fsum[t] = s;
    }
}

// ---------------- conv 7x7 s4 p3 + bias + sigmoid -> bf16 f (ch-last) + ps -
#define ROWP 532
__global__ __launch_bounds__(256) void conv_kernel(const float* __restrict__ x,
                                                   const float* __restrict__ w_t,
                                                   const float* __restrict__ bias,
                                                   ushort_t* __restrict__ f_bf,
                                                   float* __restrict__ ps) {
    __shared__ float xs[21 * ROWP];
    __shared__ float pssum[256];
    const int bid = blockIdx.x;
    const int b = bid >> 7;
    const int oh = bid & 127;
    const int tid = threadIdx.x;

    for (int i = tid; i < 21 * ROWP; i += 256) xs[i] = 0.f;
    __syncthreads();
    for (int i = tid; i < 21 * 512; i += 256) {
        int row = i >> 9;          // ci*7 + kh
        int iw  = i & 511;
        int ci = row / 7;
        int kh = row - ci * 7;
        int ih = oh * 4 - 3 + kh;  // [-3, 511]
        float v = 0.f;
        if (ih >= 0) v = x[((b * 3 + ci) * 512 + ih) * 512 + iw];
        int iwp = iw + 3;
        xs[row * ROWP + iwp + (iwp >> 5)] = v;
    }
    __syncthreads();

    const int ow = tid & 127;
    const int half = tid >> 7;
    const int half_u = __builtin_amdgcn_readfirstlane(half);
    const float* wb = w_t + half_u * 32;   // tap stride 64 floats

    float acc[32];
#pragma unroll
    for (int j = 0; j < 32; ++j) acc[j] = 0.f;

    // 2-deep ping-pong: prefetch tap t+1 weights (uniform -> s_load) while
    // doing tap t's 32 FMAs. Last prefetch reads 128B past w_t -> padded ws.
    float w0[32], w1[32];
#pragma unroll
    for (int j = 0; j < 32; ++j) w0[j] = wb[j];
    const float* wp = wb + 64;

    for (int row = 0; row < 21; ++row) {
        const int base = row * ROWP;
#pragma unroll
        for (int kw = 0; kw < 7; ++kw) {
#pragma unroll
            for (int j = 0; j < 32; ++j) w1[j] = wp[j];
            int iwp = ow * 4 + kw;
            float xv = xs[base + iwp + (iwp >> 5)];
#pragma unroll
            for (int j = 0; j < 32; ++j) acc[j] = fmaf(xv, w0[j], acc[j]);
#pragma unroll
            for (int j = 0; j < 32; ++j) w0[j] = w1[j];
            wp += 64;
        }
    }

    // bias + sigmoid; ps partial (fp32 f, matches ref); pack bf16
    const int c0 = half * 32;
    float pspart = 0.f;
    uint_t pk[16];
#pragma unroll
    for (int j = 0; j < 32; j += 2) {
        float z0 = acc[j] + bias[c0 + j];
        float z1 = acc[j + 1] + bias[c0 + j + 1];
        float f0 = 1.f / (1.f + __expf(-z0));
        float f1 = 1.f / (1.f + __expf(-z1));
        pspart = fmaf(f0, f0, pspart);
        pspart = fmaf(f1, f1, pspart);
        pk[j >> 1] = (uint_t)bf16_rne(f0) | ((uint_t)bf16_rne(f1) << 16);
    }
    long pix = (long)b * PIX + oh * 128 + ow;
    uint4* dst = (uint4*)(f_bf + pix * 64 + c0);
#pragma unroll
    for (int q = 0; q < 4; ++q)
        dst[q] = make_uint4(pk[4 * q], pk[4 * q + 1], pk[4 * q + 2], pk[4 * q + 3]);

    pssum[tid] = pspart;
    __syncthreads();
    if (half == 0) ps[pix] = pssum[tid] + pssum[tid + 128];
}

// ---------------- pp: bf16 MFMA cc + acts + fused max partials -------------
// Wave: 64 pixels x 96 protos (6 tiles of 16). Block = 4 waves = 256 pixels.
// grid = b(16) x pixgroup(64) x protohalf(2) = 2048 blocks.
// Frags loaded straight from global: channel-last => lane's 16B contiguous.
__global__ __launch_bounds__(256) void pp_kernel(const ushort_t* __restrict__ f_bf,
                                                 const float* __restrict__ ps,
                                                 const ushort_t* __restrict__ proto_bf,
                                                 const float* __restrict__ fsum,
                                                 float* __restrict__ acts,
                                                 float* __restrict__ partial) {
    const int bid = blockIdx.x;
    const int half = bid & 1;
    const int pg = (bid >> 1) & 63;
    const int b = bid >> 7;
    const int wave = threadIdx.x >> 6;
    const int lane = threadIdx.x & 63;
    const int n = lane & 15;
    const int quad = lane >> 4;

    const int wpg = pg * 4 + wave;        // 0..255 per batch
    const int pixbase = wpg * 64;
    const long fbase = (long)b * PIX + pixbase;

    // B frags: 4 pixel subtiles x 2 k-chunks
    bf16x8 bfr[4][2];
    float psv[4];
#pragma unroll
    for (int s = 0; s < 4; ++s) {
        const ushort_t* fp = f_bf + (fbase + s * 16 + n) * 64 + quad * 8;
        bfr[s][0] = *(const bf16x8*)fp;
        bfr[s][1] = *(const bf16x8*)(fp + 32);
        psv[s] = ps[fbase + s * 16 + n];
    }

    for (int pt = 0; pt < 6; ++pt) {
        const int p0 = half * 96 + pt * 16;
        const ushort_t* ap = proto_bf + (p0 + n) * 64 + quad * 8;
        bf16x8 a0 = *(const bf16x8*)ap;
        bf16x8 a1 = *(const bf16x8*)(ap + 32);
        float fs[4];
#pragma unroll
        for (int r = 0; r < 4; ++r) fs[r] = fsum[p0 + quad * 4 + r];

        f32x4 acc[4];
#pragma unroll
        for (int s = 0; s < 4; ++s) {
            acc[s] = (f32x4){0.f, 0.f, 0.f, 0.f};
            acc[s] = __builtin_amdgcn_mfma_f32_16x16x32_bf16(a0, bfr[s][0], acc[s], 0, 0, 0);
            acc[s] = __builtin_amdgcn_mfma_f32_16x16x32_bf16(a1, bfr[s][1], acc[s], 0, 0, 0);
        }

        float mx[4] = {-1e30f, -1e30f, -1e30f, -1e30f};
#pragma unroll
        for (int s = 0; s < 4; ++s) {
#pragma unroll
            for (int r = 0; r < 4; ++r) {
                float d = fmaf(-2.f, acc[s][r], psv[s] + fs[r]);
                float act = __logf(__fdividef(d + 1.f, d + EPS_F));
                mx[r] = fmaxf(mx[r], act);
                int p = p0 + quad * 4 + r;
                if (p < N_P)
                    acts[((long)(b * N_P + p) << 14) + pixbase + s * 16 + n] = act;
            }
        }
        // max over the 16 n-lanes (xor 1,2,4,8 stays within the quad's group)
#pragma unroll
        for (int r = 0; r < 4; ++r) {
            float m = mx[r];
            m = fmaxf(m, __shfl_xor(m, 1, 64));
            m = fmaxf(m, __shfl_xor(m, 2, 64));
            m = fmaxf(m, __shfl_xor(m, 4, 64));
            m = fmaxf(m, __shfl_xor(m, 8, 64));
            if (n == 0)
                partial[((long)(b * 192 + p0 + quad * 4 + r) << 8) + wpg] = m;
        }
    }
}

// ---------------- final: 256-way max per (b,p) + logits --------------------
__global__ __launch_bounds__(256) void final_kernel(const float* __restrict__ partial,
                                                    const float* __restrict__ last_w,
                                                    float* __restrict__ logits) {
    const int b = blockIdx.x;
    const int t = threadIdx.x;
    __shared__ float sm[192];
    if (t < N_P) {
        const float4* row = (const float4*)(partial + ((long)(b * 192 + t) << 8));
        float m = -1e30f;
        for (int i = 0; i < 64; ++i) {
            float4 v = row[i];
            m = fmaxf(m, fmaxf(fmaxf(v.x, v.y), fmaxf(v.z, v.w)));
        }
        sm[t] = m;
    }
    __syncthreads();
    if (t < N_CLS) {
        float s = 0.f;
        for (int p = 0; p < N_P; ++p)
            s = fmaf(sm[p], last_w[t * N_P + p], s);
        logits[b * N_CLS + t] = s;
    }
}

extern "C" void kernel_launch(void* const* d_in, const int* in_sizes, int n_in,
                              void* d_out, int out_size, void* d_ws, size_t ws_size,
                              hipStream_t stream) {
    const float* x      = (const float*)d_in[0];  // (16,3,512,512)
    const float* feat_w = (const float*)d_in[1];  // (64,3,7,7)
    const float* feat_b = (const float*)d_in[2];  // (64,)
    const float* proto  = (const float*)d_in[3];  // (190,64,1,1)
    const float* last_w = (const float*)d_in[4];  // (19,190)

    float* out_logits = (float*)d_out;                 // 304
    float* out_acts   = (float*)d_out + N_B * N_CLS;   // 16*190*128*128

    char* ws = (char*)d_ws;
    ushort_t* f_bf     = (ushort_t*)(ws);                    // 33,554,432 B
    float*    ps       = (float*)(ws + 33554432);            //  1,048,576 B
    float*    partial  = (float*)(ws + 34603008);            //  3,145,728 B
    float*    w_t      = (float*)(ws + 37748736);            //     37,632 B (+pad, OOB-prefetch safe)
    ushort_t* proto_bf = (ushort_t*)(ws + 37814272);         //     24,576 B
    float*    fsum     = (float*)(ws + 37847040);            //        768 B

    prep_kernel<<<48, 256, 0, stream>>>(feat_w, proto, w_t, proto_bf, fsum);
    conv_kernel<<<N_B * 128, 256, 0, stream>>>(x, w_t, feat_b, f_bf, ps);
    pp_kernel<<<2048, 256, 0, stream>>>(f_bf, ps, proto_bf, fsum, out_acts, partial);
    final_kernel<<<N_B, 256, 0, stream>>>(partial, last_w, out_logits);
}

// Round 3
// 333.974 us; speedup vs baseline: 2.1233x; 1.3288x over previous
//
#include <hip/hip_runtime.h>
#include <hip/hip_bf16.h>

// PPNet head for MI355X, round 3.
// prep -> conv (implicit-GEMM bf16 MFMA, writes bf16 f channel-last + fp32 ps)
//      -> pp (bf16 MFMA cc + log acts + fused max partials, single pass)
//      -> pool -> logits.
// R2 conv was s_load-latency bound (VALUBusy 38%, 151us); MFMA-ized here.

#define N_P   190
#define N_CLS 19
#define N_B   16
#define EPS_F 1e-4f

typedef unsigned short ushort_t;
typedef unsigned int   uint_t;
typedef __attribute__((ext_vector_type(8))) short bf16x8;
typedef __attribute__((ext_vector_type(4))) float f32x4;

__device__ __forceinline__ ushort_t bf16_rne(float v) {
    uint_t u = __float_as_uint(v);
    u += 0x7fffu + ((u >> 16) & 1u);
    return (ushort_t)(u >> 16);
}
__device__ __forceinline__ uint_t pack2(float a, float b) {
    return (uint_t)bf16_rne(a) | ((uint_t)bf16_rne(b) << 16);
}

// ---------------- prep ------------------------------------------------------
// wf[kr][co][kw'] bf16, kr in [0,24), kw' in [0,8):
//   kw'=0 or kr>=21 -> 0; else w[co][ci*49+kh*7+(kw'-1)], (ci,kh) = kr /% 7.
// Zero weight columns absorb all K-padding so conv's A-gather needs no masks.
// Also proto_bf (padded to 192) and fsum.
__global__ void prep_kernel(const float* __restrict__ feat_w,
                            const float* __restrict__ proto,
                            ushort_t* __restrict__ wf,
                            ushort_t* __restrict__ proto_bf,
                            float* __restrict__ fsum) {
    int t = blockIdx.x * 256 + threadIdx.x;   // grid 48*256 = 12288
    if (t < 12288) {
        int kr = t >> 9, co = (t >> 3) & 63, kwp = t & 7;
        float v = 0.f;
        if (kr < 21 && kwp >= 1) {
            int ci = kr / 7, kh = kr - ci * 7;
            v = feat_w[co * 147 + ci * 49 + kh * 7 + (kwp - 1)];
        }
        wf[t] = bf16_rne(v);
        int p = t >> 6, c = t & 63;
        proto_bf[t] = bf16_rne((p < N_P) ? proto[p * 64 + c] : 0.f);
    }
    if (t < 192) {
        float s = 0.f;
        if (t < N_P)
            for (int c = 0; c < 64; ++c) {
                float v = proto[t * 64 + c];
                s = fmaf(v, v, s);
            }
        fsum[t] = s;
    }
}

// ---------------- conv: implicit GEMM, 7x7 s4 p3 + bias + sigmoid ----------
// Block = 4 waves = 2 output rows (oh pair); wave = 1 row-half: 64 pix x 64 co.
// LDS: x as bf16, 33 rows (3ci x 11ih) x 520 (4-elem left pad -> all b64
// staging writes and patch gathers 8B-aligned). A=weights from global
// (24KB frag layout, L1-hot); B=patches from LDS. D: row=co, col=pixel ->
// lane stores 4 contiguous co as one 8B write (L2 merges segments).
#define XW 520
__global__ __launch_bounds__(256) void conv_kernel(const float* __restrict__ x,
                                                   const ushort_t* __restrict__ wf,
                                                   const float* __restrict__ bias,
                                                   ushort_t* __restrict__ f_bf,
                                                   float* __restrict__ ps) {
    __shared__ ushort_t xs[33 * XW];
    const int b  = blockIdx.x >> 6;
    const int op = blockIdx.x & 63;
    const int tid = threadIdx.x;

    if (tid < 33) *(uint2*)(xs + tid * XW) = make_uint2(0u, 0u);  // left pad
    const int base_ih = op * 8 - 3;
    for (int i = tid; i < 33 * 128; i += 256) {
        int row = i >> 7;
        int c4  = (i & 127) << 2;
        int ci  = (row * 94) >> 10;      // row/11 for row<33
        int ihr = row - ci * 11;
        int ih  = base_ih + ihr;
        float4 v = make_float4(0.f, 0.f, 0.f, 0.f);
        if (ih >= 0 && ih < 512)
            v = *(const float4*)(x + (((b * 3 + ci) * 512 + ih) << 9) + c4);
        uint2 pk = make_uint2(pack2(v.x, v.y), pack2(v.z, v.w));
        *(uint2*)(xs + row * XW + c4 + 4) = pk;   // byte = row*1040 + 2*c4+8, 8B-aligned
    }
    __syncthreads();

    const int lane = tid & 63, wave = tid >> 6;
    const int n = lane & 15, quad = lane >> 4;
    const int oh_l = wave >> 1, owb = (wave & 1) << 6;

    f32x4 acc[4][4];
#pragma unroll
    for (int ms = 0; ms < 4; ++ms)
#pragma unroll
        for (int ns = 0; ns < 4; ++ns) acc[ms][ns] = (f32x4){0.f, 0.f, 0.f, 0.f};

#pragma unroll
    for (int c = 0; c < 6; ++c) {
        const int kr  = c * 4 + quad;               // k-row 0..23
        const int kra = (kr < 21) ? kr : 0;         // clamp; B weight rows >=21 are 0
        const int ci  = (kra * 37) >> 8;            // kra/7
        const int kh  = kra - ci * 7;
        const ushort_t* bb = xs + (ci * 11 + oh_l * 4 + kh) * XW;

        bf16x8 afr[4], bfr[4];
        const ushort_t* wbase = wf + (kr << 9) + (n << 3);
#pragma unroll
        for (int ms = 0; ms < 4; ++ms)
            afr[ms] = *(const bf16x8*)(wbase + (ms << 7));   // 16B aligned
#pragma unroll
        for (int ns = 0; ns < 4; ++ns) {
            const ushort_t* p8 = bb + ((owb + ns * 16 + n) << 2);  // 8B aligned
            union { uint2 u[2]; bf16x8 v; } t2;
            t2.u[0] = *(const uint2*)(p8);
            t2.u[1] = *(const uint2*)(p8 + 4);
            bfr[ns] = t2.v;
        }
#pragma unroll
        for (int ms = 0; ms < 4; ++ms)
#pragma unroll
            for (int ns = 0; ns < 4; ++ns)
                acc[ms][ns] = __builtin_amdgcn_mfma_f32_16x16x32_bf16(
                    afr[ms], bfr[ns], acc[ms][ns], 0, 0, 0);
    }

    // Epilogue: lane holds co = ms*16+quad*4+r, pixel = owb+ns*16+n.
    const int oh = op * 2 + oh_l;
    const long pixrow = (long)b * 16384 + oh * 128 + owb;
    float psl[4] = {0.f, 0.f, 0.f, 0.f};
#pragma unroll
    for (int ms = 0; ms < 4; ++ms) {
        float4 bv = *(const float4*)(bias + ms * 16 + quad * 4);
        const float* bvp = (const float*)&bv;
#pragma unroll
        for (int ns = 0; ns < 4; ++ns) {
            float fr[4];
#pragma unroll
            for (int r = 0; r < 4; ++r) {
                float z = acc[ms][ns][r] + bvp[r];
                float f = 1.f / (1.f + __expf(-z));
                fr[r] = f;
                psl[ns] = fmaf(f, f, psl[ns]);
            }
            uint2 pk = make_uint2(pack2(fr[0], fr[1]), pack2(fr[2], fr[3]));
            *(uint2*)(f_bf + (pixrow + ns * 16 + n) * 64 + ms * 16 + quad * 4) = pk;
        }
    }
#pragma unroll
    for (int ns = 0; ns < 4; ++ns) {   // fold quads -> full sum over 64 co
        float v = psl[ns];
        v += __shfl_xor(v, 16, 64);
        v += __shfl_xor(v, 32, 64);
        if (quad == 0) ps[pixrow + ns * 16 + n] = v;
    }
}

// ---------------- pp: bf16 MFMA cc + acts + fused max partials -------------
// Wave: 32 pixels x all 192 protos (12 tiles); f frags read once.
// grid = b(16) x pg(128) = 2048 blocks x 4 waves -> 8 waves/SIMD.
__global__ __launch_bounds__(256) void pp_kernel(const ushort_t* __restrict__ f_bf,
                                                 const float* __restrict__ ps,
                                                 const ushort_t* __restrict__ proto_bf,
                                                 const float* __restrict__ fsum,
                                                 float* __restrict__ acts,
                                                 float* __restrict__ partial) {
    const int b  = blockIdx.x >> 7;
    const int pg = blockIdx.x & 127;
    const int tid = threadIdx.x, lane = tid & 63, wave = tid >> 6;
    const int n = lane & 15, quad = lane >> 4;
    const int wpg = pg * 4 + wave;            // 0..511
    const int pixbase = wpg * 32;
    const long fbase = (long)b * 16384 + pixbase;

    bf16x8 bfr[2][2];
    float psv[2];
#pragma unroll
    for (int s = 0; s < 2; ++s) {
        const ushort_t* fp = f_bf + (fbase + s * 16 + n) * 64 + quad * 8;
        bfr[s][0] = *(const bf16x8*)fp;
        bfr[s][1] = *(const bf16x8*)(fp + 32);
        psv[s] = ps[fbase + s * 16 + n];
    }

    for (int pt = 0; pt < 12; ++pt) {
        const int p0 = pt * 16;
        const ushort_t* ap = proto_bf + (p0 + n) * 64 + quad * 8;
        bf16x8 a0 = *(const bf16x8*)ap;
        bf16x8 a1 = *(const bf16x8*)(ap + 32);
        float4 fsv = *(const float4*)(fsum + p0 + quad * 4);
        const float* fsp = (const float*)&fsv;

        f32x4 acc[2];
#pragma unroll
        for (int s = 0; s < 2; ++s) {
            acc[s] = (f32x4){0.f, 0.f, 0.f, 0.f};
            acc[s] = __builtin_amdgcn_mfma_f32_16x16x32_bf16(a0, bfr[s][0], acc[s], 0, 0, 0);
            acc[s] = __builtin_amdgcn_mfma_f32_16x16x32_bf16(a1, bfr[s][1], acc[s], 0, 0, 0);
        }

        float mx[4] = {-1e30f, -1e30f, -1e30f, -1e30f};
#pragma unroll
        for (int s = 0; s < 2; ++s) {
#pragma unroll
            for (int r = 0; r < 4; ++r) {
                float d = fmaf(-2.f, acc[s][r], psv[s] + fsp[r]);
                float act = __logf(__fdividef(d + 1.f, d + EPS_F));
                mx[r] = fmaxf(mx[r], act);
                int p = p0 + quad * 4 + r;
                if (p < N_P)
                    acts[((long)(b * N_P + p) << 14) + pixbase + s * 16 + n] = act;
            }
        }
#pragma unroll
        for (int r = 0; r < 4; ++r) {
            float m = mx[r];
            m = fmaxf(m, __shfl_xor(m, 1, 64));
            m = fmaxf(m, __shfl_xor(m, 2, 64));
            m = fmaxf(m, __shfl_xor(m, 4, 64));
            m = fmaxf(m, __shfl_xor(m, 8, 64));
            if (n == 0)
                partial[((long)(b * 192 + p0 + quad * 4 + r) << 9) + wpg] = m;
        }
    }
}

// ---------------- pool: 512-way max per (b,p) ------------------------------
__global__ void pool_kernel(const float* __restrict__ partial,
                            float* __restrict__ pooled) {
    const int idx = blockIdx.x;               // b*190 + p
    const int b = idx / 190, p = idx - b * 190;
    const float4* base = (const float4*)(partial + ((long)(b * 192 + p) << 9));
    const int t = threadIdx.x;                // 64
    float4 v0 = base[t * 2], v1 = base[t * 2 + 1];
    float m = fmaxf(fmaxf(fmaxf(v0.x, v0.y), fmaxf(v0.z, v0.w)),
                    fmaxf(fmaxf(v1.x, v1.y), fmaxf(v1.z, v1.w)));
#pragma unroll
    for (int off = 32; off; off >>= 1) m = fmaxf(m, __shfl_xor(m, off, 64));
    if (t == 0) pooled[idx] = m;
}

// ---------------- logits ---------------------------------------------------
__global__ void logits_kernel(const float* __restrict__ pooled,
                              const float* __restrict__ last_w,
                              float* __restrict__ logits) {
    int t = blockIdx.x * blockDim.x + threadIdx.x;
    if (t >= N_B * N_CLS) return;
    int b = t / N_CLS, cls = t - b * N_CLS;
    float s = 0.f;
    for (int p = 0; p < N_P; ++p)
        s = fmaf(pooled[b * N_P + p], last_w[cls * N_P + p], s);
    logits[t] = s;
}

extern "C" void kernel_launch(void* const* d_in, const int* in_sizes, int n_in,
                              void* d_out, int out_size, void* d_ws, size_t ws_size,
                              hipStream_t stream) {
    const float* x      = (const float*)d_in[0];  // (16,3,512,512)
    const float* feat_w = (const float*)d_in[1];  // (64,3,7,7)
    const float* feat_b = (const float*)d_in[2];  // (64,)
    const float* proto  = (const float*)d_in[3];  // (190,64,1,1)
    const float* last_w = (const float*)d_in[4];  // (19,190)

    float* out_logits = (float*)d_out;                 // 304
    float* out_acts   = (float*)d_out + N_B * N_CLS;   // 16*190*128*128

    char* ws = (char*)d_ws;
    ushort_t* f_bf     = (ushort_t*)(ws);                    // 33,554,432 B
    float*    ps       = (float*)(ws + 33554432);            //  1,048,576 B
    float*    partial  = (float*)(ws + 34603008);            //  6,291,456 B (16*192*512)
    ushort_t* wf       = (ushort_t*)(ws + 40894464);         //     24,576 B
    ushort_t* proto_bf = (ushort_t*)(ws + 40919040);         //     24,576 B
    float*    fsum     = (float*)(ws + 40943616);            //        768 B
    float*    pooled   = (float*)(ws + 40944384);            //     12,160 B

    prep_kernel<<<48, 256, 0, stream>>>(feat_w, proto, wf, proto_bf, fsum);
    conv_kernel<<<N_B * 64, 256, 0, stream>>>(x, wf, feat_b, f_bf, ps);
    pp_kernel<<<N_B * 128, 256, 0, stream>>>(f_bf, ps, proto_bf, fsum, out_acts, partial);
    pool_kernel<<<N_B * N_P, 64, 0, stream>>>(partial, pooled);
    logits_kernel<<<2, 256, 0, stream>>>(pooled, last_w, out_logits);
}